// Round 6
// baseline (121.935 us; speedup 1.0000x reference)
//
#include <hip/hip_runtime.h>
#include <hip/hip_bf16.h>

typedef __attribute__((ext_vector_type(8))) short s8v;            // 8 x bf16
typedef __attribute__((ext_vector_type(4))) float f4v;            // 4 x f32

__device__ __forceinline__ short f2bf(float f) {
    __hip_bfloat16 h = __float2bfloat16(f);
    union { __hip_bfloat16 h; short s; } u{h};
    return u.s;
}
__device__ __forceinline__ float bf2f(unsigned short v) {
    union { unsigned u; float f; } x; x.u = ((unsigned)v) << 16; return x.f;
}

// ---------------------------------------------------------------------------
// pack kernel: pack the four weight matrices into bf16 B-fragment order for
// mfma_16x16x32_bf16: frag f = ks*8+n; lane l holds
// W[ks*32+(l>>4)*8+e][n*16+(l&15)], e=0..7.   40 blocks x 256 thr.
// ---------------------------------------------------------------------------
__global__ void pack_kernel(const float* __restrict__ w1c, const float* __restrict__ w2c,
                            const float* __restrict__ w1f, const float* __restrict__ w2f,
                            short* __restrict__ p1c, short* __restrict__ p2c,
                            short* __restrict__ p1f, short* __restrict__ p2f)
{
    int id = blockIdx.x * 256 + threadIdx.x;   // 10240 = 160 frags * 64 lanes
    int f  = id >> 6, l = id & 63;
    const float* W; short* P; int fl;
    if      (f < 64)  { W = w1c; P = p1c; fl = f; }        // K=256: 64 frags
    else if (f < 96)  { W = w2c; P = p2c; fl = f - 64; }   // K=128: 32 frags
    else if (f < 128) { W = w1f; P = p1f; fl = f - 96; }
    else              { W = w2f; P = p2f; fl = f - 128; }
    int g = l >> 4, c = l & 15;
    int ks = fl >> 3, n = fl & 7;
    s8v o;
    #pragma unroll
    for (int e = 0; e < 8; ++e)
        o[e] = f2bf(W[(ks*32 + g*8 + e) * 128 + n*16 + c]);
    *(s8v*)(P + ((fl*64 + l) << 3)) = o;
}

// ---------------------------------------------------------------------------
// Fused MFMA MLP, 64 rows per WAVE (4 A-fragments), 256 rows per block.
// 256 threads = 4 waves. __launch_bounds__(256,2) -> ~256 unified regs/wave:
// acc[4][8] lives in AGPR (128), leaving ~120 VGPRs so the batched weight /
// A-fragment loads can stay in flight (this was the R3-R5 serialization bug:
// compiler allocated 40 VGPRs and emitted load->waitcnt chains).
// First nWinBlocks blocks instead do winner atomicMax resolution.
// ---------------------------------------------------------------------------
template<int K1, bool FINE>
__global__ __launch_bounds__(256, 2)
void mlp_mfma(const float* __restrict__ X,
              const short* __restrict__ Wp1,
              const float* __restrict__ g1v, const float* __restrict__ b1v,
              const short* __restrict__ Wp2,
              const float* __restrict__ g2v, const float* __restrict__ b2v,
              float* __restrict__ outF,            // FINE: f32 output
              unsigned short* __restrict__ outB,   // !FINE: bf16 fc output
              const int* __restrict__ winner,
              const unsigned short* __restrict__ fcB,
              const int* __restrict__ nr, const int* __restrict__ nc,
              int* __restrict__ win, int nWinBlocks)
{
    // per-wave 64x128 bf16 slice; 16B-granule XOR-row swizzle (no pad).
    __shared__ short H[4][64][128];   // 64 KB

    if (blockIdx.x < (unsigned)nWinBlocks) {
        int i = blockIdx.x * 256 + threadIdx.x;
        atomicMax(&win[nr[i] * 32 + nc[i]], i);
        return;
    }
    const int bid = blockIdx.x - nWinBlocks;

    const int t = threadIdx.x;
    const int wave = t >> 6, lane = t & 63;
    const int g = lane >> 4, c = lane & 15;
    const int wrow = bid * 256 + wave * 64;

    // prefetch winner: lane l holds winner for local row l (64 rows/wave)
    int wv = 0;
    if constexpr (FINE) wv = winner[wrow + lane];

    float G1[8], B1[8];
    #pragma unroll
    for (int n = 0; n < 8; ++n) { G1[n] = g1v[n*16 + c]; B1[n] = b1v[n*16 + c]; }

    // ---------- Layer 1: H1 = X @ W1 ----------
    f4v acc[4][8];
    #pragma unroll
    for (int s = 0; s < 4; ++s)
        #pragma unroll
        for (int n = 0; n < 8; ++n) acc[s][n] = (f4v){0.f, 0.f, 0.f, 0.f};

    const short* wp1 = Wp1 + (lane << 3);
    #pragma unroll
    for (int ks = 0; ks < K1/32; ++ks) {
        s8v bfr[8];
        #pragma unroll
        for (int n = 0; n < 8; ++n)
            bfr[n] = *(const s8v*)(wp1 + ((ks*8 + n) << 9));
        s8v af[4];
        #pragma unroll
        for (int s = 0; s < 4; ++s) {
            const float* p = X + (size_t)(wrow + s*16 + c) * K1 + ks*32 + g*8;
            float4 a0 = *(const float4*)p;
            float4 a1 = *(const float4*)(p + 4);
            s8v v;
            v[0] = f2bf(a0.x); v[1] = f2bf(a0.y); v[2] = f2bf(a0.z); v[3] = f2bf(a0.w);
            v[4] = f2bf(a1.x); v[5] = f2bf(a1.y); v[6] = f2bf(a1.z); v[7] = f2bf(a1.w);
            af[s] = v;
        }
        #pragma unroll
        for (int s = 0; s < 4; ++s)
            #pragma unroll
            for (int n = 0; n < 8; ++n)
                acc[s][n] = __builtin_amdgcn_mfma_f32_16x16x32_bf16(af[s], bfr[n], acc[s][n], 0, 0, 0);
    }

    // ---------- LN1 -> LDS (granule-XOR swizzle) ----------
    #pragma unroll
    for (int s = 0; s < 4; ++s) {
        #pragma unroll
        for (int j = 0; j < 4; ++j) {
            float sm = 0.f, sq = 0.f;
            #pragma unroll
            for (int n = 0; n < 8; ++n) { float v = acc[s][n][j]; sm += v; sq += v*v; }
            #pragma unroll
            for (int m = 1; m < 16; m <<= 1) {
                sm += __shfl_xor(sm, m, 64);
                sq += __shfl_xor(sq, m, 64);
            }
            float mean = sm * (1.f/128.f);
            float rstd = rsqrtf(sq * (1.f/128.f) - mean*mean + 1e-5f);
            int row = s*16 + g*4 + j;
            #pragma unroll
            for (int n = 0; n < 8; ++n) {
                float y = (acc[s][n][j] - mean) * rstd * G1[n] + B1[n];
                int col = n*16 + c;
                int phys = (((col >> 3) ^ (row & 15)) << 3) | (col & 7);
                H[wave][row][phys] = f2bf(y);
            }
        }
    }

    // ---------- Layer 2: H2 = H1 @ W2 ----------
    f4v acc2[4][8];
    #pragma unroll
    for (int s = 0; s < 4; ++s)
        #pragma unroll
        for (int n = 0; n < 8; ++n) acc2[s][n] = (f4v){0.f, 0.f, 0.f, 0.f};

    const short* wp2 = Wp2 + (lane << 3);
    #pragma unroll
    for (int ks = 0; ks < 4; ++ks) {
        s8v bfr[8];
        #pragma unroll
        for (int n = 0; n < 8; ++n)
            bfr[n] = *(const s8v*)(wp2 + ((ks*8 + n) << 9));
        s8v af[4];
        #pragma unroll
        for (int s = 0; s < 4; ++s)
            af[s] = *(const s8v*)&H[wave][s*16 + c][((ks*4 + g) ^ c) << 3];
        #pragma unroll
        for (int s = 0; s < 4; ++s)
            #pragma unroll
            for (int n = 0; n < 8; ++n)
                acc2[s][n] = __builtin_amdgcn_mfma_f32_16x16x32_bf16(af[s], bfr[n], acc2[s][n], 0, 0, 0);
    }

    // ---------- LN2 + ReLU -> LDS (same swizzle) ----------
    float G2[8], B2[8];
    #pragma unroll
    for (int n = 0; n < 8; ++n) { G2[n] = g2v[n*16 + c]; B2[n] = b2v[n*16 + c]; }
    #pragma unroll
    for (int s = 0; s < 4; ++s) {
        #pragma unroll
        for (int j = 0; j < 4; ++j) {
            float sm = 0.f, sq = 0.f;
            #pragma unroll
            for (int n = 0; n < 8; ++n) { float v = acc2[s][n][j]; sm += v; sq += v*v; }
            #pragma unroll
            for (int m = 1; m < 16; m <<= 1) {
                sm += __shfl_xor(sm, m, 64);
                sq += __shfl_xor(sq, m, 64);
            }
            float mean = sm * (1.f/128.f);
            float rstd = rsqrtf(sq * (1.f/128.f) - mean*mean + 1e-5f);
            int row = s*16 + g*4 + j;
            #pragma unroll
            for (int n = 0; n < 8; ++n) {
                float y = fmaxf((acc2[s][n][j] - mean) * rstd * G2[n] + B2[n], 0.f);
                int col = n*16 + c;
                int phys = (((col >> 3) ^ (row & 15)) << 3) | (col & 7);
                H[wave][row][phys] = f2bf(y);
            }
        }
    }

    // ---------- coalesced writeback (per-wave LDS slice, no barrier) -------
    // iteration it: rows it*4+g; lane reads granule c of its row.
    #pragma unroll
    for (int it = 0; it < 16; ++it) {
        int row = it*4 + g;
        int R   = wrow + row;
        s8v v = *(const s8v*)&H[wave][row][(c ^ (row & 15)) << 3];
        if constexpr (FINE) {
            float y8[8];
            #pragma unroll
            for (int e = 0; e < 8; ++e) y8[e] = bf2f((unsigned short)v[e]);
            int w = __shfl(wv, row, 64);
            if (w >= 0) {
                const s8v u = *(const s8v*)(fcB + (size_t)(w & 32767) * 128 + c*8);
                #pragma unroll
                for (int e = 0; e < 8; ++e) y8[e] += bf2f((unsigned short)u[e]);
            }
            float4 o0 = {y8[0], y8[1], y8[2], y8[3]};
            float4 o1 = {y8[4], y8[5], y8[6], y8[7]};
            float* op = outF + (size_t)R * 128 + c*8;
            *(float4*)op       = o0;
            *(float4*)(op + 4) = o1;
        } else {
            *(s8v*)(outB + (size_t)R * 128 + c*8) = v;
        }
    }
}

extern "C" void kernel_launch(void* const* d_in, const int* in_sizes, int n_in,
                              void* d_out, int out_size, void* d_ws, size_t ws_size,
                              hipStream_t stream)
{
    const float* fcoarse = (const float*)d_in[0];
    const float* ffine   = (const float*)d_in[1];
    const float* w1c = (const float*)d_in[2];
    const float* g1c = (const float*)d_in[3];
    const float* b1c = (const float*)d_in[4];
    const float* w2c = (const float*)d_in[5];
    const float* g2c = (const float*)d_in[6];
    const float* b2c = (const float*)d_in[7];
    const float* w1f = (const float*)d_in[8];
    const float* g1f = (const float*)d_in[9];
    const float* b1f = (const float*)d_in[10];
    const float* w2f = (const float*)d_in[11];
    const float* g2f = (const float*)d_in[12];
    const float* b2f = (const float*)d_in[13];
    const int* nrow  = (const int*)d_in[14];
    const int* ncol  = (const int*)d_in[15];

    float* out = (float*)d_out;

    const int Mc = 32768, Mf = 131072;

    // workspace: fcB (bf16, 8MB) | winner (512KB) | packed weights (160KB)
    unsigned short* fcB = (unsigned short*)d_ws;
    char* base = (char*)d_ws;
    int*   winner = (int*)(base + 8u*1024*1024);
    short* p1c = (short*)(base + 8u*1024*1024 + 512u*1024);
    short* p2c = p1c + 256*128;
    short* p1f = p2c + 128*128;
    short* p2f = p1f + 128*128;

    hipMemsetAsync(winner, 0xFF, (size_t)Mf * sizeof(int), stream);
    pack_kernel<<<40, 256, 0, stream>>>(w1c, w2c, w1f, w2f, p1c, p2c, p1f, p2f);

    // coarse MLP (128 blocks) + winner resolution (1024 blocks) in one dispatch
    mlp_mfma<256, false><<<1024 + Mc/256, 256, 0, stream>>>(
        fcoarse, p1c, g1c, b1c, p2c, g2c, b2c,
        nullptr, fcB, nullptr, nullptr,
        nrow, ncol, winner, 1024);

    // fine MLP + fused scatter -> out (512 blocks)
    mlp_mfma<128, true><<<Mf/256, 256, 0, stream>>>(
        ffine, p1f, g1f, b1f, p2f, g2f, b2f,
        out, nullptr, winner, fcB,
        nullptr, nullptr, nullptr, 0);
}

// Round 7
// 102.642 us; speedup vs baseline: 1.1880x; 1.1880x over previous
//
#include <hip/hip_runtime.h>
#include <hip/hip_bf16.h>

typedef __attribute__((ext_vector_type(8))) short s8v;            // 8 x bf16
typedef __attribute__((ext_vector_type(4))) float f4v;            // 4 x f32

__device__ __forceinline__ short f2bf(float f) {
    __hip_bfloat16 h = __float2bfloat16(f);
    union { __hip_bfloat16 h; short s; } u{h};
    return u.s;
}
__device__ __forceinline__ float bf2f(unsigned short v) {
    union { unsigned u; float f; } x; x.u = ((unsigned)v) << 16; return x.f;
}

// ---------------------------------------------------------------------------
// prep kernel: blocks [0,1024) winner atomicMax; blocks [1024,1064) pack the
// four weight matrices into bf16 B-fragment order for mfma_16x16x32_bf16:
//   frag f = ks*8+n; lane l holds W[ks*32+(l>>4)*8+e][n*16+(l&15)], e=0..7.
// ---------------------------------------------------------------------------
__global__ void prep_kernel(const int* __restrict__ nr, const int* __restrict__ nc,
                            int* __restrict__ win,
                            const float* __restrict__ w1c, const float* __restrict__ w2c,
                            const float* __restrict__ w1f, const float* __restrict__ w2f,
                            short* __restrict__ p1c, short* __restrict__ p2c,
                            short* __restrict__ p1f, short* __restrict__ p2f)
{
    int b = blockIdx.x, t = threadIdx.x;
    if (b < 1024) {
        int i = b * 256 + t;
        atomicMax(&win[nr[i] * 32 + nc[i]], i);
        return;
    }
    int id = (b - 1024) * 256 + t;        // 40*256 = 160 frags * 64 lanes
    int f  = id >> 6, l = id & 63;
    const float* W; short* P; int fl;
    if      (f < 64)  { W = w1c; P = p1c; fl = f; }        // K=256: 64 frags
    else if (f < 96)  { W = w2c; P = p2c; fl = f - 64; }   // K=128: 32 frags
    else if (f < 128) { W = w1f; P = p1f; fl = f - 96; }
    else              { W = w2f; P = p2f; fl = f - 128; }
    int g = l >> 4, c = l & 15;
    int ks = fl >> 3, n = fl & 7;
    s8v o;
    #pragma unroll
    for (int e = 0; e < 8; ++e)
        o[e] = f2bf(W[(ks*32 + g*8 + e) * 128 + n*16 + c]);
    *(s8v*)(P + ((fl*64 + l) << 3)) = o;
}

// ---------------------------------------------------------------------------
// Fused MFMA MLP with LDS-resident weights.
// 256 thr = 4 waves; 16 rows/wave, 64 rows/tile; grid-stride over tiles.
// All global loads (A-fragments, gather rows) prefetched into register
// arrays so only ONE latency exposure per group (the R2-R6 serialization
// bug was per-load waitcnt chains on L2-latency weight reads).
// ---------------------------------------------------------------------------
template<int K1, bool FINE>
__global__ __launch_bounds__(256, 2)
void mlp_mfma(const float* __restrict__ X,
              const short* __restrict__ Wp1,
              const float* __restrict__ g1v, const float* __restrict__ b1v,
              const short* __restrict__ Wp2,
              const float* __restrict__ g2v, const float* __restrict__ b2v,
              float* __restrict__ outF,            // FINE: f32 output
              unsigned short* __restrict__ outB,   // !FINE: bf16 fc output
              const int* __restrict__ winner,
              const unsigned short* __restrict__ fcB,
              int nTiles)
{
    constexpr int NF1 = (K1/32) * 8;       // W1 fragments
    __shared__ short W1s[NF1 * 512];       // frag-major copy of packed W1
    __shared__ short W2s[32  * 512];
    __shared__ short H[4][16][128];        // per-wave LN bounce, XOR-swizzled

    const int t = threadIdx.x;
    const int wave = t >> 6, lane = t & 63;
    const int g = lane >> 4, c = lane & 15;

    // ---- stage weights to LDS (reg-staged, chunked 8 to bound VGPRs) ----
    {
        const s8v* src1 = (const s8v*)Wp1;   // NF1*64 16B chunks
        #pragma unroll
        for (int base = 0; base < NF1*64; base += 2048) {
            s8v tmp[8];
            #pragma unroll
            for (int u = 0; u < 8; ++u) tmp[u] = src1[base + u*256 + t];
            #pragma unroll
            for (int u = 0; u < 8; ++u) *(s8v*)&W1s[(base + u*256 + t) * 8] = tmp[u];
        }
        const s8v* src2 = (const s8v*)Wp2;   // 2048 chunks
        {
            s8v tmp[8];
            #pragma unroll
            for (int u = 0; u < 8; ++u) tmp[u] = src2[u*256 + t];
            #pragma unroll
            for (int u = 0; u < 8; ++u) *(s8v*)&W2s[(u*256 + t) * 8] = tmp[u];
        }
    }
    __syncthreads();

    float G1[8], B1[8], G2[8], B2[8];
    #pragma unroll
    for (int n = 0; n < 8; ++n) {
        G1[n] = g1v[n*16 + c]; B1[n] = b1v[n*16 + c];
        G2[n] = g2v[n*16 + c]; B2[n] = b2v[n*16 + c];
    }

    for (int tile = blockIdx.x; tile < nTiles; tile += gridDim.x) {
        const int wrow = tile * 64 + wave * 16;

        int wv = 0;
        if constexpr (FINE) wv = winner[wrow + c];   // lane c holds row c

        // ---- prefetch ALL A-fragments (one latency exposure) ----
        float4 aPf[K1/32][2];
        const float* pX = X + (size_t)(wrow + c) * K1 + g*8;
        #pragma unroll
        for (int ks = 0; ks < K1/32; ++ks) {
            aPf[ks][0] = *(const float4*)(pX + ks*32);
            aPf[ks][1] = *(const float4*)(pX + ks*32 + 4);
        }

        // ---- Layer 1: H1 = X @ W1 (weights from LDS) ----
        f4v acc[8];
        #pragma unroll
        for (int n = 0; n < 8; ++n) acc[n] = (f4v){0.f, 0.f, 0.f, 0.f};
        #pragma unroll
        for (int ks = 0; ks < K1/32; ++ks) {
            s8v bfr[8];
            #pragma unroll
            for (int n = 0; n < 8; ++n)
                bfr[n] = *(const s8v*)&W1s[((ks*8 + n)*64 + lane) * 8];
            s8v af;
            af[0] = f2bf(aPf[ks][0].x); af[1] = f2bf(aPf[ks][0].y);
            af[2] = f2bf(aPf[ks][0].z); af[3] = f2bf(aPf[ks][0].w);
            af[4] = f2bf(aPf[ks][1].x); af[5] = f2bf(aPf[ks][1].y);
            af[6] = f2bf(aPf[ks][1].z); af[7] = f2bf(aPf[ks][1].w);
            #pragma unroll
            for (int n = 0; n < 8; ++n)
                acc[n] = __builtin_amdgcn_mfma_f32_16x16x32_bf16(af, bfr[n], acc[n], 0, 0, 0);
        }

        // ---- LN1 -> H (granule-XOR swizzle) ----
        #pragma unroll
        for (int j = 0; j < 4; ++j) {
            float sm = 0.f, sq = 0.f;
            #pragma unroll
            for (int n = 0; n < 8; ++n) { float v = acc[n][j]; sm += v; sq += v*v; }
            #pragma unroll
            for (int m = 1; m < 16; m <<= 1) {
                sm += __shfl_xor(sm, m, 64);
                sq += __shfl_xor(sq, m, 64);
            }
            float mean = sm * (1.f/128.f);
            float rstd = rsqrtf(sq * (1.f/128.f) - mean*mean + 1e-5f);
            int row = g*4 + j;
            #pragma unroll
            for (int n = 0; n < 8; ++n) {
                float y = (acc[n][j] - mean) * rstd * G1[n] + B1[n];
                int col = n*16 + c;
                int phys = (((col >> 3) ^ row) << 3) | (col & 7);
                H[wave][row][phys] = f2bf(y);
            }
        }

        // ---- Layer 2: H2 = H1 @ W2 (both operands from LDS) ----
        f4v acc2[8];
        #pragma unroll
        for (int n = 0; n < 8; ++n) acc2[n] = (f4v){0.f, 0.f, 0.f, 0.f};
        #pragma unroll
        for (int ks = 0; ks < 4; ++ks) {
            s8v bfr[8];
            #pragma unroll
            for (int n = 0; n < 8; ++n)
                bfr[n] = *(const s8v*)&W2s[((ks*8 + n)*64 + lane) * 8];
            s8v af = *(const s8v*)&H[wave][c][((ks*4 + g) ^ c) << 3];
            #pragma unroll
            for (int n = 0; n < 8; ++n)
                acc2[n] = __builtin_amdgcn_mfma_f32_16x16x32_bf16(af, bfr[n], acc2[n], 0, 0, 0);
        }

        // ---- LN2 + ReLU -> H (same swizzle) ----
        #pragma unroll
        for (int j = 0; j < 4; ++j) {
            float sm = 0.f, sq = 0.f;
            #pragma unroll
            for (int n = 0; n < 8; ++n) { float v = acc2[n][j]; sm += v; sq += v*v; }
            #pragma unroll
            for (int m = 1; m < 16; m <<= 1) {
                sm += __shfl_xor(sm, m, 64);
                sq += __shfl_xor(sq, m, 64);
            }
            float mean = sm * (1.f/128.f);
            float rstd = rsqrtf(sq * (1.f/128.f) - mean*mean + 1e-5f);
            int row = g*4 + j;
            #pragma unroll
            for (int n = 0; n < 8; ++n) {
                float y = fmaxf((acc2[n][j] - mean) * rstd * G2[n] + B2[n], 0.f);
                int col = n*16 + c;
                int phys = (((col >> 3) ^ row) << 3) | (col & 7);
                H[wave][row][phys] = f2bf(y);
            }
        }

        // ---- writeback: rows it*4+g, lane reads granule c of its row ----
        if constexpr (FINE) {
            // prefetch all 4 gather rows (one latency exposure)
            s8v gv[4]; int wl[4];
            #pragma unroll
            for (int it = 0; it < 4; ++it) {
                int row = it*4 + g;
                int w = __shfl(wv, row, 64);
                wl[it] = w;
                if (w >= 0)
                    gv[it] = *(const s8v*)(fcB + (size_t)(w & 32767) * 128 + c*8);
            }
            #pragma unroll
            for (int it = 0; it < 4; ++it) {
                int row = it*4 + g;
                int R   = wrow + row;
                s8v v = *(const s8v*)&H[wave][row][(c ^ row) << 3];
                float y8[8];
                #pragma unroll
                for (int e = 0; e < 8; ++e) y8[e] = bf2f((unsigned short)v[e]);
                if (wl[it] >= 0) {
                    #pragma unroll
                    for (int e = 0; e < 8; ++e) y8[e] += bf2f((unsigned short)gv[it][e]);
                }
                float4 o0 = {y8[0], y8[1], y8[2], y8[3]};
                float4 o1 = {y8[4], y8[5], y8[6], y8[7]};
                float* op = outF + (size_t)R * 128 + c*8;
                *(float4*)op       = o0;
                *(float4*)(op + 4) = o1;
            }
        } else {
            #pragma unroll
            for (int it = 0; it < 4; ++it) {
                int row = it*4 + g;
                int R   = wrow + row;
                s8v v = *(const s8v*)&H[wave][row][(c ^ row) << 3];
                *(s8v*)(outB + (size_t)R * 128 + c*8) = v;
            }
        }
    }
}

extern "C" void kernel_launch(void* const* d_in, const int* in_sizes, int n_in,
                              void* d_out, int out_size, void* d_ws, size_t ws_size,
                              hipStream_t stream)
{
    const float* fcoarse = (const float*)d_in[0];
    const float* ffine   = (const float*)d_in[1];
    const float* w1c = (const float*)d_in[2];
    const float* g1c = (const float*)d_in[3];
    const float* b1c = (const float*)d_in[4];
    const float* w2c = (const float*)d_in[5];
    const float* g2c = (const float*)d_in[6];
    const float* b2c = (const float*)d_in[7];
    const float* w1f = (const float*)d_in[8];
    const float* g1f = (const float*)d_in[9];
    const float* b1f = (const float*)d_in[10];
    const float* w2f = (const float*)d_in[11];
    const float* g2f = (const float*)d_in[12];
    const float* b2f = (const float*)d_in[13];
    const int* nrow  = (const int*)d_in[14];
    const int* ncol  = (const int*)d_in[15];

    float* out = (float*)d_out;

    const int Mf = 131072;

    // workspace: fcB (bf16, 8MB) | winner (512KB) | packed weights (160KB)
    unsigned short* fcB = (unsigned short*)d_ws;
    char* base = (char*)d_ws;
    int*   winner = (int*)(base + 8u*1024*1024);
    short* p1c = (short*)(base + 8u*1024*1024 + 512u*1024);
    short* p2c = p1c + 256*128;
    short* p1f = p2c + 128*128;
    short* p2f = p1f + 128*128;

    hipMemsetAsync(winner, 0xFF, (size_t)Mf * sizeof(int), stream);
    prep_kernel<<<1064, 256, 0, stream>>>(nrow, ncol, winner,
                                          w1c, w2c, w1f, w2f,
                                          p1c, p2c, p1f, p2f);

    // coarse MLP -> fcB: 512 tiles of 64 rows
    mlp_mfma<256, false><<<512, 256, 0, stream>>>(
        fcoarse, p1c, g1c, b1c, p2c, g2c, b2c,
        nullptr, fcB, nullptr, nullptr, 512);

    // fine MLP + fused scatter -> out: 2048 tiles, 2 per block
    mlp_mfma<128, true><<<1024, 256, 0, stream>>>(
        ffine, p1f, g1f, b1f, p2f, g2f, b2f,
        out, nullptr, winner, fcB, 2048);
}

// Round 8
// 93.165 us; speedup vs baseline: 1.3088x; 1.1017x over previous
//
#include <hip/hip_runtime.h>
#include <hip/hip_bf16.h>

typedef __attribute__((ext_vector_type(8))) short s8v;            // 8 x bf16
typedef __attribute__((ext_vector_type(4))) float f4v;            // 4 x f32

__device__ __forceinline__ short f2bf(float f) {
    __hip_bfloat16 h = __float2bfloat16(f);
    union { __hip_bfloat16 h; short s; } u{h};
    return u.s;
}
__device__ __forceinline__ float bf2f(unsigned short v) {
    union { unsigned u; float f; } x; x.u = ((unsigned)v) << 16; return x.f;
}
__device__ __forceinline__ unsigned packbf(float a, float b) {
    return (unsigned)(unsigned short)f2bf(a) | ((unsigned)(unsigned short)f2bf(b) << 16);
}

// ---------------------------------------------------------------------------
// prep: blocks [0,40) pack weights (W2 packs pre-scaled by g1: W2' = g1 o W2)
// into the MFMA fragment order (frag f=ks*8+n: lane l, elem e holds
// W[ks*32+(l>>4)*8+e][n*16+(l&15)]); blocks 40/41 compute the LN1-folding
// vectors s2[c] = colsum(bf16(W2')), bW2[c] = b1 @ W2.
// ---------------------------------------------------------------------------
__global__ void prep_kernel(const float* __restrict__ w1c, const float* __restrict__ w2c,
                            const float* __restrict__ g1c, const float* __restrict__ b1c,
                            const float* __restrict__ w1f, const float* __restrict__ w2f,
                            const float* __restrict__ g1f, const float* __restrict__ b1f,
                            short* __restrict__ p1c, short* __restrict__ p2c,
                            short* __restrict__ p1f, short* __restrict__ p2f,
                            float* __restrict__ s2c, float* __restrict__ bwc,
                            float* __restrict__ s2f, float* __restrict__ bwf)
{
    int b = blockIdx.x, t = threadIdx.x;
    if (b >= 40) {                       // folding vectors
        if (t >= 128) return;
        const float* W  = (b == 40) ? w2c : w2f;
        const float* g1 = (b == 40) ? g1c : g1f;
        const float* b1 = (b == 40) ? b1c : b1f;
        float* s2 = (b == 40) ? s2c : s2f;
        float* bw = (b == 40) ? bwc : bwf;
        float s = 0.f, w2sum = 0.f;
        for (int k = 0; k < 128; ++k) {
            float wv = W[k * 128 + t];
            s     += bf2f((unsigned short)f2bf(g1[k] * wv));  // match MFMA operand rounding
            w2sum += b1[k] * wv;
        }
        s2[t] = s; bw[t] = w2sum;
        return;
    }
    int id = b * 256 + t;                 // 40*256 = 160 frags * 64 lanes
    int f  = id >> 6, l = id & 63;
    const float* W; const float* g1 = nullptr; short* P; int fl;
    if      (f < 64)  { W = w1c; P = p1c; fl = f; }                   // K=256
    else if (f < 96)  { W = w2c; P = p2c; fl = f - 64;  g1 = g1c; }   // scaled
    else if (f < 128) { W = w1f; P = p1f; fl = f - 96; }
    else              { W = w2f; P = p2f; fl = f - 128; g1 = g1f; }   // scaled
    int g = l >> 4, c = l & 15;
    int ks = fl >> 3, n = fl & 7;
    s8v o;
    #pragma unroll
    for (int e = 0; e < 8; ++e) {
        int k = ks*32 + g*8 + e;
        float v = W[k * 128 + n*16 + c];
        if (g1) v *= g1[k];
        o[e] = f2bf(v);
    }
    *(s8v*)(P + ((fl*64 + l) << 3)) = o;
}

// ---------------------------------------------------------------------------
// Swapped-orientation fused MLP: compute H^T = W^T @ X^T so each lane owns
// one full output row (x_row = lane&15) -> LN reductions are lane-local
// partials + 2 shuffle rounds; LN1 folded into W2' (prep) so layer 2 runs on
// RAW H1; zero LDS, zero barriers.
// Lane l, fragment mt: holds T[mt*16 + (l>>4)*4 + j][x_row l&15].
// First nWinBlocks blocks do winner atomicMax resolution instead.
// ---------------------------------------------------------------------------
template<int K1, bool FINE>
__global__ __launch_bounds__(256, 4)
void mlp_mfma(const float* __restrict__ X,
              const short* __restrict__ WpA,     // packed W1 (A-operand)
              const short* __restrict__ WpB,     // packed W2' (A-operand)
              const float* __restrict__ s2v, const float* __restrict__ bwv,
              const float* __restrict__ g2v, const float* __restrict__ b2v,
              float* __restrict__ outF,            // FINE: f32 output
              unsigned short* __restrict__ outB,   // !FINE: bf16 fc output
              const int* __restrict__ winner,
              const unsigned short* __restrict__ fcB,
              const int* __restrict__ nr, const int* __restrict__ nc,
              int* __restrict__ win, int nWinBlocks)
{
    if (blockIdx.x < (unsigned)nWinBlocks) {
        int i = blockIdx.x * 256 + threadIdx.x;
        atomicMax(&win[nr[i] * 32 + nc[i]], i);
        return;
    }
    const int bid  = blockIdx.x - nWinBlocks;
    const int t    = threadIdx.x;
    const int wave = t >> 6, lane = t & 63;
    const int G = lane >> 4, n16 = lane & 15;
    const int row = bid * 64 + wave * 16 + n16;      // this lane's x_row
    const size_t rowK = (size_t)row * K1;

    int wv = 0;
    if constexpr (FINE) wv = winner[row];

    // ---------------- Layer 1: acc1 = W1^T @ X^T ----------------
    f4v acc1[8];
    #pragma unroll
    for (int mt = 0; mt < 8; ++mt) acc1[mt] = (f4v){0.f, 0.f, 0.f, 0.f};

    const short* wpa = WpA + (lane << 3);
    const float* pX  = X + rowK + G*8;
    #pragma unroll
    for (int kb = 0; kb < K1/32; kb += 4) {
        float4 aPf[4][2];
        #pragma unroll
        for (int k2 = 0; k2 < 4; ++k2) {
            aPf[k2][0] = *(const float4*)(pX + (kb + k2)*32);
            aPf[k2][1] = *(const float4*)(pX + (kb + k2)*32 + 4);
        }
        #pragma unroll
        for (int k2 = 0; k2 < 4; ++k2) {
            const int ks = kb + k2;
            s8v wfr[8];
            #pragma unroll
            for (int mt = 0; mt < 8; ++mt)
                wfr[mt] = *(const s8v*)(wpa + ((ks*8 + mt) << 9));
            s8v xf;
            xf[0] = f2bf(aPf[k2][0].x); xf[1] = f2bf(aPf[k2][0].y);
            xf[2] = f2bf(aPf[k2][0].z); xf[3] = f2bf(aPf[k2][0].w);
            xf[4] = f2bf(aPf[k2][1].x); xf[5] = f2bf(aPf[k2][1].y);
            xf[6] = f2bf(aPf[k2][1].z); xf[7] = f2bf(aPf[k2][1].w);
            #pragma unroll
            for (int mt = 0; mt < 8; ++mt)
                acc1[mt] = __builtin_amdgcn_mfma_f32_16x16x32_bf16(wfr[mt], xf, acc1[mt], 0, 0, 0);
        }
    }

    // ---------------- stats1 (lane-local + 2 shuffle rounds) ----------------
    float sm = 0.f, sq = 0.f;
    #pragma unroll
    for (int mt = 0; mt < 8; ++mt)
        #pragma unroll
        for (int j = 0; j < 4; ++j) { float v = acc1[mt][j]; sm += v; sq += v*v; }
    sm += __shfl_xor(sm, 16, 64); sm += __shfl_xor(sm, 32, 64);
    sq += __shfl_xor(sq, 16, 64); sq += __shfl_xor(sq, 32, 64);
    const float mean1 = sm * (1.f/128.f);
    const float rstd1 = rsqrtf(sq * (1.f/128.f) - mean1*mean1 + 1e-5f);

    // pack raw H1 to bf16 pairs (LN1 folded into W2'/s2/bW2)
    unsigned pk[8][2];
    #pragma unroll
    for (int mt = 0; mt < 8; ++mt) {
        pk[mt][0] = packbf(acc1[mt][0], acc1[mt][1]);
        pk[mt][1] = packbf(acc1[mt][2], acc1[mt][3]);
    }

    // ---------------- Layer 2: acc2 = W2'^T @ H1^T ----------------
    // B-frag element e (k = ks*32+8G+e) lives in lane group 2(G&1)(+1), reg
    // j=e&3, fragment mt=2ks+(G>>1): build via 8 shuffles + 4 selects per ks.
    f4v acc2[8];
    #pragma unroll
    for (int mt = 0; mt < 8; ++mt) acc2[mt] = (f4v){0.f, 0.f, 0.f, 0.f};

    const short* wpb = WpB + (lane << 3);
    const int src0 = ((G & 1) << 5) + n16;    // group 2(G&1), same x_row
    const int src1 = src0 + 16;
    const bool hiG = (G >= 2);
    #pragma unroll
    for (int ks = 0; ks < 4; ++ks) {
        int r00 = __shfl((int)pk[2*ks][0],   src0, 64);
        int r01 = __shfl((int)pk[2*ks][1],   src0, 64);
        int r02 = __shfl((int)pk[2*ks][0],   src1, 64);
        int r03 = __shfl((int)pk[2*ks][1],   src1, 64);
        int r10 = __shfl((int)pk[2*ks+1][0], src0, 64);
        int r11 = __shfl((int)pk[2*ks+1][1], src0, 64);
        int r12 = __shfl((int)pk[2*ks+1][0], src1, 64);
        int r13 = __shfl((int)pk[2*ks+1][1], src1, 64);
        union { int u[4]; s8v v; } hb;
        hb.u[0] = hiG ? r10 : r00; hb.u[1] = hiG ? r11 : r01;
        hb.u[2] = hiG ? r12 : r02; hb.u[3] = hiG ? r13 : r03;
        s8v wfr[8];
        #pragma unroll
        for (int mt = 0; mt < 8; ++mt)
            wfr[mt] = *(const s8v*)(wpb + ((ks*8 + mt) << 9));
        #pragma unroll
        for (int mt = 0; mt < 8; ++mt)
            acc2[mt] = __builtin_amdgcn_mfma_f32_16x16x32_bf16(wfr[mt], hb.v, acc2[mt], 0, 0, 0);
    }

    // ---------------- folded LN1 apply + stats2 ----------------
    float h2[8][4];
    float sm2 = 0.f, sq2 = 0.f;
    #pragma unroll
    for (int mt = 0; mt < 8; ++mt) {
        const int col = mt*16 + G*4;
        f4v s2l = *(const f4v*)&s2v[col];
        f4v bwl = *(const f4v*)&bwv[col];
        #pragma unroll
        for (int j = 0; j < 4; ++j) {
            float v = rstd1 * (acc2[mt][j] - mean1 * s2l[j]) + bwl[j];
            h2[mt][j] = v; sm2 += v; sq2 += v*v;
        }
    }
    sm2 += __shfl_xor(sm2, 16, 64); sm2 += __shfl_xor(sm2, 32, 64);
    sq2 += __shfl_xor(sq2, 16, 64); sq2 += __shfl_xor(sq2, 32, 64);
    const float mean2 = sm2 * (1.f/128.f);
    const float rstd2 = rsqrtf(sq2 * (1.f/128.f) - mean2*mean2 + 1e-5f);

    // ---------------- LN2 + ReLU + (FINE: gather-add) + store ----------------
    if constexpr (FINE) {
        ushort4 gv[8];
        const bool hasw = (wv >= 0);
        const size_t src = (size_t)(wv & 32767) * 128;
        if (hasw) {
            #pragma unroll
            for (int mt = 0; mt < 8; ++mt)
                gv[mt] = *(const ushort4*)(fcB + src + mt*16 + G*4);
        }
        #pragma unroll
        for (int mt = 0; mt < 8; ++mt) {
            const int col = mt*16 + G*4;
            f4v g2l = *(const f4v*)&g2v[col];
            f4v b2l = *(const f4v*)&b2v[col];
            float4 o;
            float z0 = fmaxf((h2[mt][0]-mean2)*rstd2*g2l[0] + b2l[0], 0.f);
            float z1 = fmaxf((h2[mt][1]-mean2)*rstd2*g2l[1] + b2l[1], 0.f);
            float z2 = fmaxf((h2[mt][2]-mean2)*rstd2*g2l[2] + b2l[2], 0.f);
            float z3 = fmaxf((h2[mt][3]-mean2)*rstd2*g2l[3] + b2l[3], 0.f);
            if (hasw) {
                z0 += bf2f(gv[mt].x); z1 += bf2f(gv[mt].y);
                z2 += bf2f(gv[mt].z); z3 += bf2f(gv[mt].w);
            }
            o.x = z0; o.y = z1; o.z = z2; o.w = z3;
            *(float4*)(outF + (size_t)row * 128 + col) = o;
        }
    } else {
        #pragma unroll
        for (int mt = 0; mt < 8; ++mt) {
            const int col = mt*16 + G*4;
            f4v g2l = *(const f4v*)&g2v[col];
            f4v b2l = *(const f4v*)&b2v[col];
            ushort4 o;
            o.x = (unsigned short)f2bf(fmaxf((h2[mt][0]-mean2)*rstd2*g2l[0] + b2l[0], 0.f));
            o.y = (unsigned short)f2bf(fmaxf((h2[mt][1]-mean2)*rstd2*g2l[1] + b2l[1], 0.f));
            o.z = (unsigned short)f2bf(fmaxf((h2[mt][2]-mean2)*rstd2*g2l[2] + b2l[2], 0.f));
            o.w = (unsigned short)f2bf(fmaxf((h2[mt][3]-mean2)*rstd2*g2l[3] + b2l[3], 0.f));
            *(ushort4*)(outB + (size_t)row * 128 + col) = o;
        }
    }
}

extern "C" void kernel_launch(void* const* d_in, const int* in_sizes, int n_in,
                              void* d_out, int out_size, void* d_ws, size_t ws_size,
                              hipStream_t stream)
{
    const float* fcoarse = (const float*)d_in[0];
    const float* ffine   = (const float*)d_in[1];
    const float* w1c = (const float*)d_in[2];
    const float* g1c = (const float*)d_in[3];
    const float* b1c = (const float*)d_in[4];
    const float* w2c = (const float*)d_in[5];
    const float* g2c = (const float*)d_in[6];
    const float* b2c = (const float*)d_in[7];
    const float* w1f = (const float*)d_in[8];
    const float* g1f = (const float*)d_in[9];
    const float* b1f = (const float*)d_in[10];
    const float* w2f = (const float*)d_in[11];
    const float* g2f = (const float*)d_in[12];
    const float* b2f = (const float*)d_in[13];
    const int* nrow  = (const int*)d_in[14];
    const int* ncol  = (const int*)d_in[15];

    float* out = (float*)d_out;
    const int Mc = 32768, Mf = 131072;

    // ws: fcB 8MB | winner 512KB | packs 160KB | fold vecs 2KB
    unsigned short* fcB = (unsigned short*)d_ws;
    char* base = (char*)d_ws;
    int*   winner = (int*)(base + 8u*1024*1024);
    short* p1c = (short*)(base + 8u*1024*1024 + 512u*1024);
    short* p2c = p1c + 256*128;
    short* p1f = p2c + 128*128;
    short* p2f = p1f + 128*128;
    float* s2c = (float*)(p2f + 128*128);
    float* bwc = s2c + 128;
    float* s2f = bwc + 128;
    float* bwf = s2f + 128;

    hipMemsetAsync(winner, 0xFF, (size_t)Mf * sizeof(int), stream);
    prep_kernel<<<42, 256, 0, stream>>>(w1c, w2c, g1c, b1c, w1f, w2f, g1f, b1f,
                                        p1c, p2c, p1f, p2f, s2c, bwc, s2f, bwf);

    // coarse MLP (512 blocks) + winner resolution (1024 blocks), one dispatch
    mlp_mfma<256, false><<<1024 + Mc/64, 256, 0, stream>>>(
        fcoarse, p1c, p2c, s2c, bwc, g2c, b2c,
        nullptr, fcB, nullptr, nullptr,
        nrow, ncol, winner, 1024);

    // fine MLP + fused scatter -> out
    mlp_mfma<128, true><<<Mf/64, 256, 0, stream>>>(
        ffine, p1f, p2f, s2f, bwf, g2f, b2f,
        out, nullptr, winner, fcB,
        nullptr, nullptr, nullptr, 0);
}